// Round 7
// baseline (59.548 us; speedup 1.0000x reference)
//
#include <hip/hip_runtime.h>
#include <cmath>

#define THREADS 256
#define QC 24000
#define NCLS 80
#define NTOP 300
#define NHIST 4096
#define CAP 1024

typedef unsigned long long ull;
typedef float f32x4 __attribute__((ext_vector_type(4)));

// monotonic unsigned key for fp32 (total order matching float compare)
__device__ __forceinline__ unsigned fkey(float x) {
    unsigned b = __float_as_uint(x);
    return (b & 0x80000000u) ? ~b : (b | 0x80000000u);
}
__device__ __forceinline__ float fkey_inv(unsigned key) {
    unsigned b = (key & 0x80000000u) ? (key & 0x7fffffffu) : ~key;
    return __uint_as_float(b);
}
// Replicate float32 sigmoid: 1/(1+expf(-x)); double exp rounds to CR expf.
__device__ __forceinline__ float sigmoid_ref(float x) {
    float ef = (float)exp(-(double)x);
    return 1.0f / (1.0f + ef);
}

// Speculative static threshold: rank-300 logit ~2.24 for this data; 2.11
// keeps ~420 +- 20 candidates/row. Checked on-device; exact histogram
// fallback below if any row violates [NTOP, CAP].
#define T0 2.11f

__global__ __launch_bounds__(THREADS, 4) void postproc_kernel(
    const float* __restrict__ logits,   // [B, 300, 80]
    const float* __restrict__ pboxes,   // [B, 300, 4]
    const float* __restrict__ osizes,   // [B, 2]
    float* __restrict__ out_boxes,      // [B, 300, 4]
    float* __restrict__ out_labels,     // [B, 300]
    float* __restrict__ out_scores,     // [B, 300]
    int B)
{
    const int b0 = blockIdx.x * 2;              // this block's rows: b0, b0+1
    const int nrows = (B - b0 >= 2) ? 2 : 1;
    const int tid = threadIdx.x;
    const int lane = tid & 63;

    __shared__ ull cand[2][CAP];            // 16 KB
    __shared__ unsigned hist[NHIST / 2];    // 8 KB packed u16 (fallback only)
    __shared__ unsigned wsum[THREADS / 64];
    __shared__ int s_nc[2];
    __shared__ unsigned s_thresh;

    if (tid < 2) s_nc[tid] = 0;
    __syncthreads();

    // ---- single streaming pass over BOTH rows (contiguous 48000 floats) ----
    const f32x4* __restrict__ base4 = (const f32x4*)(logits + (size_t)b0 * QC);
    const int n4 = nrows * (QC / 4);

    auto pushe = [&](float x, int e) {          // e in [0, nrows*QC)
        if (x >= T0) {
            int r = (e >= QC) ? 1 : 0;
            int p = atomicAdd(&s_nc[r], 1);
            if (p < CAP) {
                unsigned idx = (unsigned)(e - r * QC);
                cand[r][p] = ((ull)fkey(x) << 32) | (ull)(~idx);
            }
        }
    };
    auto handle = [&](f32x4 v, int i) {
        pushe(v.x, 4 * i);     pushe(v.y, 4 * i + 1);
        pushe(v.z, 4 * i + 2); pushe(v.w, 4 * i + 3);
    };

    int i = tid;
    for (; i + 7 * THREADS < n4; i += 8 * THREADS) {
        f32x4 v0 = __builtin_nontemporal_load(base4 + i);
        f32x4 v1 = __builtin_nontemporal_load(base4 + i + THREADS);
        f32x4 v2 = __builtin_nontemporal_load(base4 + i + 2 * THREADS);
        f32x4 v3 = __builtin_nontemporal_load(base4 + i + 3 * THREADS);
        f32x4 v4 = __builtin_nontemporal_load(base4 + i + 4 * THREADS);
        f32x4 v5 = __builtin_nontemporal_load(base4 + i + 5 * THREADS);
        f32x4 v6 = __builtin_nontemporal_load(base4 + i + 6 * THREADS);
        f32x4 v7 = __builtin_nontemporal_load(base4 + i + 7 * THREADS);
        handle(v0, i);               handle(v1, i + THREADS);
        handle(v2, i + 2 * THREADS); handle(v3, i + 3 * THREADS);
        handle(v4, i + 4 * THREADS); handle(v5, i + 5 * THREADS);
        handle(v6, i + 6 * THREADS); handle(v7, i + 7 * THREADS);
    }
    for (; i < n4; i += THREADS)
        handle(__builtin_nontemporal_load(base4 + i), i);
    __syncthreads();

    int nc[2];
    nc[0] = s_nc[0];
    nc[1] = (nrows == 2) ? s_nc[1] : 0;

    // ---- exact histogram fallback, per row (rare; block-uniform branch) ----
    for (int r = 0; r < nrows; ++r) {
        if (nc[r] >= NTOP && nc[r] <= CAP) continue;
        const f32x4* __restrict__ row4 =
            (const f32x4*)(logits + (size_t)(b0 + r) * QC);
        for (int j = tid; j < NHIST / 2; j += THREADS) hist[j] = 0u;
        __syncthreads();
        for (int j = tid; j < QC / 4; j += THREADS) {
            f32x4 v = row4[j];
            float vals[4] = {v.x, v.y, v.z, v.w};
            #pragma unroll
            for (int s = 0; s < 4; ++s) {
                unsigned bin = fkey(vals[s]) >> 20;
                atomicAdd(&hist[bin >> 1], (bin & 1) ? 0x10000u : 1u);
            }
        }
        __syncthreads();
        const int CHUNK = NHIST / THREADS;          // 16
        const int base = NHIST - 1 - tid * CHUNK;
        unsigned partial = 0;
        #pragma unroll
        for (int s = 0; s < CHUNK; ++s) {
            int bin = base - s;
            partial += (hist[bin >> 1] >> ((bin & 1) * 16)) & 0xffffu;
        }
        unsigned run = partial;
        #pragma unroll
        for (int d = 1; d < 64; d <<= 1) {
            unsigned v = __shfl_up(run, d, 64);
            if (lane >= d) run += v;
        }
        if (lane == 63) wsum[tid >> 6] = run;
        __syncthreads();
        unsigned off = 0;
        for (int w = 0; w < (tid >> 6); ++w) off += wsum[w];
        unsigned incl = run + off, excl = incl - partial;
        if (excl < NTOP && incl >= NTOP) {
            unsigned cum = excl;
            #pragma unroll
            for (int s = 0; s < CHUNK; ++s) {
                int bin = base - s;
                cum += (hist[bin >> 1] >> ((bin & 1) * 16)) & 0xffffu;
                if (cum >= NTOP) { s_thresh = (unsigned)bin << 20; break; }
            }
        }
        if (tid == 0) s_nc[r] = 0;
        __syncthreads();
        const unsigned T = s_thresh;
        for (int j = tid; j < QC / 4; j += THREADS) {
            f32x4 v = row4[j];
            float vals[4] = {v.x, v.y, v.z, v.w};
            #pragma unroll
            for (int s = 0; s < 4; ++s) {
                unsigned kk = fkey(vals[s]);
                if (kk >= T) {
                    int pos = atomicAdd(&s_nc[r], 1);
                    if (pos < CAP)
                        cand[r][pos] = ((ull)kk << 32)
                                     | (ull)(~(unsigned)(4 * j + s));
                }
            }
        }
        __syncthreads();
        nc[r] = min(s_nc[r], CAP);
    }

    // ---- dense sigmoid over both rows' candidates (key -> score bits) ----
    const int tot = nc[0] + nc[1];
    for (int j2 = tid; j2 < tot; j2 += THREADS) {
        int r = (j2 >= nc[0]) ? 1 : 0;
        int j = j2 - (r ? nc[0] : 0);
        ull c = cand[r][j];
        float sc = sigmoid_ref(fkey_inv((unsigned)(c >> 32)));
        cand[r][j] = ((ull)__float_as_uint(sc) << 32) | (c & 0xffffffffull);
    }

    int npad[2];
    npad[0] = 512; while (npad[0] < nc[0]) npad[0] <<= 1;
    npad[1] = 512; while (npad[1] < nc[1]) npad[1] <<= 1;
    for (int j = nc[0] + tid; j < npad[0]; j += THREADS) cand[0][j] = 0ull;
    for (int j = nc[1] + tid; j < npad[1]; j += THREADS) cand[1][j] = 0ull;
    __syncthreads();

    if (nrows == 2 && npad[0] == 512 && npad[1] == 512) {
        // ==== dual interleaved bitonic-512, wave-local stages barrier-free ====
        // pair index p = tid; stages with j<=64 live inside the 128-element
        // segment [128w, 128w+128) owned by wave w -> no __syncthreads needed
        // (compiler-inserted lgkmcnt orders same-wave LDS RAW). Only j=128,256
        // cross waves.
        bool prev_cross = false;
        for (int k = 2; k <= 512; k <<= 1) {
            for (int j = k >> 1; j > 0; j >>= 1) {
                bool cross = (j >= 128);
                if (cross || prev_cross) __syncthreads();
                int u = ((tid & ~(j - 1)) << 1) | (tid & (j - 1));
                int uxj = u | j;
                bool desc = (u & k) == 0;
                ull a0 = cand[0][u], c0 = cand[0][uxj];
                ull a1 = cand[1][u], c1 = cand[1][uxj];
                if (desc ? (a0 < c0) : (a0 > c0)) { cand[0][u] = c0; cand[0][uxj] = a0; }
                if (desc ? (a1 < c1) : (a1 > c1)) { cand[1][u] = c1; cand[1][uxj] = a1; }
                prev_cross = cross;
            }
        }
        __syncthreads();
    } else {
        // rare: generic barrier-per-stage bitonic per row (npad up to 1024)
        for (int r = 0; r < nrows; ++r) {
            int np = npad[r];
            for (int k = 2; k <= np; k <<= 1) {
                for (int j = k >> 1; j > 0; j >>= 1) {
                    for (int t = tid; t < (np >> 1); t += THREADS) {
                        int u = ((t & ~(j - 1)) << 1) | (t & (j - 1));
                        int uxj = u | j;
                        ull a = cand[r][u], c = cand[r][uxj];
                        bool desc = (u & k) == 0;
                        if (desc ? (a < c) : (a > c)) {
                            cand[r][u] = c; cand[r][uxj] = a;
                        }
                    }
                    __syncthreads();
                }
            }
        }
    }

    // ---- emit top-300 for both rows ----
    for (int r = 0; r < nrows; ++r) {
        const int row = b0 + r;
        const float o0 = osizes[2 * row], o1 = osizes[2 * row + 1];
        const float4* __restrict__ pb4 = (const float4*)pboxes + (size_t)row * NTOP;
        float4* __restrict__ ob4 = (float4*)out_boxes + (size_t)row * NTOP;
        auto emit = [&](int rk) {
            ull c = cand[r][rk];
            float sc = __uint_as_float((unsigned)(c >> 32));
            unsigned idx = ~((unsigned)c);
            unsigned q = idx / NCLS;
            unsigned cls = idx - q * NCLS;
            out_scores[(size_t)row * NTOP + rk] = sc;
            out_labels[(size_t)row * NTOP + rk] = (float)cls;
            float4 pb = pb4[q];
            float4 ob;
            ob.x = (pb.x - 0.5f * pb.z) * o0;
            ob.y = (pb.y - 0.5f * pb.w) * o1;
            ob.z = (pb.x + 0.5f * pb.z) * o0;
            ob.w = (pb.y + 0.5f * pb.w) * o1;
            ob4[rk] = ob;
        };
        emit(tid);
        if (tid < NTOP - 256) emit(tid + 256);
    }
}

extern "C" void kernel_launch(void* const* d_in, const int* in_sizes, int n_in,
                              void* d_out, int out_size, void* d_ws, size_t ws_size,
                              hipStream_t stream) {
    const float* logits = (const float*)d_in[0];
    const float* pboxes = (const float*)d_in[1];
    const float* osizes = (const float*)d_in[2];
    const int B = in_sizes[2] / 2;

    float* out_boxes  = (float*)d_out;                       // B*300*4
    float* out_labels = out_boxes + (size_t)B * NTOP * 4;    // B*300
    float* out_scores = out_labels + (size_t)B * NTOP;       // B*300

    const int nblk = (B + 1) / 2;
    hipLaunchKernelGGL(postproc_kernel, dim3(nblk), dim3(THREADS), 0, stream,
                       logits, pboxes, osizes, out_boxes, out_labels, out_scores, B);
}